// Round 3
// baseline (314.184 us; speedup 1.0000x reference)
//
#include <hip/hip_runtime.h>
#include <hip/hip_bf16.h>
#include <float.h>

#define H 2048
#define E 64
#define TOPK 8
#define TT 16    // tokens per block
#define NT 256   // threads per block (4 waves)

typedef __attribute__((ext_vector_type(8))) short bf16x8;
typedef __attribute__((ext_vector_type(4))) float f32x4;
typedef __attribute__((ext_vector_type(4))) unsigned short us4;

__device__ __forceinline__ unsigned short f2bf(float f) {
  unsigned u = __float_as_uint(f);
  u += 0x7fffu + ((u >> 16) & 1u);   // RNE
  return (unsigned short)(u >> 16);
}
__device__ __forceinline__ float bf2f(unsigned short s) {
  return __uint_as_float(((unsigned)s) << 16);
}
__device__ __forceinline__ float wred_max(float v) {
#pragma unroll
  for (int o = 32; o > 0; o >>= 1) v = fmaxf(v, __shfl_xor(v, o));
  return v;
}
__device__ __forceinline__ float wred_sum(float v) {
#pragma unroll
  for (int o = 32; o > 0; o >>= 1) v += __shfl_xor(v, o);
  return v;
}

// Convert router_weight and expert_bias fp32 -> bf16 into workspace (L2-resident).
__global__ __launch_bounds__(256) void cvt_kernel(const float* __restrict__ W,
                                                  const float* __restrict__ eb,
                                                  unsigned short* __restrict__ Wb,
                                                  unsigned short* __restrict__ Bb) {
  int i = (blockIdx.x * 256 + threadIdx.x) * 4;
  const float* src;
  unsigned short* dst;
  int off;
  if (i < E * H) { src = W; dst = Wb; off = i; }
  else           { src = eb; dst = Bb; off = i - E * H; }
  float4 v = *(const float4*)(src + off);
  us4 r;
  r[0] = f2bf(v.x); r[1] = f2bf(v.y); r[2] = f2bf(v.z); r[3] = f2bf(v.w);
  *(us4*)(dst + off) = r;
}

template <bool USE_WS>
__global__ __launch_bounds__(NT, 4) void moe_kernel(
    const float* __restrict__ x, const float* __restrict__ W,
    const float* __restrict__ rb, const float* __restrict__ eb,
    const unsigned short* __restrict__ Wb, const unsigned short* __restrict__ Bb,
    float* __restrict__ out) {
  // Small LDS only: logits + top-k metadata (~5 KB) -> 4+ blocks/CU co-resident.
  __shared__ float lg[TT][E + 1];
  __shared__ float msw[TT];
  __shared__ float mw[TT][TOPK];
  __shared__ int   mi[TT][TOPK];

  const int tid = threadIdx.x;
  const int t0  = blockIdx.x * TT;
  const int wv = tid >> 6, lane = tid & 63, quad = lane >> 4, m = lane & 15;

  // ---- Phase B: logits[16 tok x 64 exp] via MFMA, A-frags straight from global x.
  // A-frag mapping (verified): A[row = lane&15][k = quad*8 + j]. The wave's 64
  // lanes cover rows 0..15 x a contiguous 32-col span -> full 64B lines touched.
  {
    const int e = wv * 16 + m;
    f32x4 acc = {0.f, 0.f, 0.f, 0.f};
    const float* xp = x + (size_t)(t0 + m) * H + quad * 8;
    if (USE_WS) {
      const unsigned short* wp = Wb + (size_t)e * H + quad * 8;
#pragma unroll 4
      for (int it = 0; it < H / 32; ++it) {
        float4 p = *(const float4*)(xp + it * 32);
        float4 q = *(const float4*)(xp + it * 32 + 4);
        bf16x8 av;
        av[0] = (short)f2bf(p.x); av[1] = (short)f2bf(p.y);
        av[2] = (short)f2bf(p.z); av[3] = (short)f2bf(p.w);
        av[4] = (short)f2bf(q.x); av[5] = (short)f2bf(q.y);
        av[6] = (short)f2bf(q.z); av[7] = (short)f2bf(q.w);
        bf16x8 bv = *(const bf16x8*)(wp + it * 32);
        acc = __builtin_amdgcn_mfma_f32_16x16x32_bf16(av, bv, acc, 0, 0, 0);
      }
    } else {
      const float* wp = W + (size_t)e * H + quad * 8;
#pragma unroll 2
      for (int it = 0; it < H / 32; ++it) {
        float4 p = *(const float4*)(xp + it * 32);
        float4 q = *(const float4*)(xp + it * 32 + 4);
        bf16x8 av;
        av[0] = (short)f2bf(p.x); av[1] = (short)f2bf(p.y);
        av[2] = (short)f2bf(p.z); av[3] = (short)f2bf(p.w);
        av[4] = (short)f2bf(q.x); av[5] = (short)f2bf(q.y);
        av[6] = (short)f2bf(q.z); av[7] = (short)f2bf(q.w);
        float4 wp0 = *(const float4*)(wp + it * 32);
        float4 wq0 = *(const float4*)(wp + it * 32 + 4);
        bf16x8 bv;
        bv[0] = (short)f2bf(wp0.x); bv[1] = (short)f2bf(wp0.y);
        bv[2] = (short)f2bf(wp0.z); bv[3] = (short)f2bf(wp0.w);
        bv[4] = (short)f2bf(wq0.x); bv[5] = (short)f2bf(wq0.y);
        bv[6] = (short)f2bf(wq0.z); bv[7] = (short)f2bf(wq0.w);
        acc = __builtin_amdgcn_mfma_f32_16x16x32_bf16(av, bv, acc, 0, 0, 0);
      }
    }
    // C/D layout (verified): col = lane&15 (expert-in-tile), row = quad*4+reg (token)
#pragma unroll
    for (int r = 0; r < 4; ++r) lg[quad * 4 + r][wv * 16 + m] = acc[r];
  }
  __syncthreads();

  // ---- Phase B': softmax + top-8. Wave wv handles tokens 4wv..4wv+3; lane = expert.
  {
#pragma unroll
    for (int tt = 0; tt < 4; ++tt) {
      const int t = wv * 4 + tt;
      float l = lg[t][lane] + rb[lane];
      const float mx = wred_max(l);
      const float p = expf(l - mx);
      const float inv = 1.f / wred_sum(p);
      float sumw = 0.f;
      float lsel = l;
#pragma unroll
      for (int k = 0; k < TOPK; ++k) {
        const float mk = wred_max(lsel);
        const unsigned long long b = __ballot(lsel == mk);
        const int idx = __ffsll(b) - 1;          // tie -> lowest index (matches top_k)
        const float wk = expf(mk - mx) * inv;
        sumw += wk;
        if (lane == 0) { mw[t][k] = wk; mi[t][k] = idx; }
        if (lane == idx) lsel = -FLT_MAX;
      }
      if (lane == 0) msw[t] = sumw;
    }
  }
  __syncthreads();

  // ---- Phase C: out[t][h] = x[t][h]*sum_w + sum_k w_k * bias[idx_k][h].
  // x re-read from global as fp32 (L2-hot from phase B) -> exact x*sumw term.
  {
    const int c = tid * 8;  // 0..2040, 256 threads cover a full row
    for (int t = 0; t < TT; ++t) {
      const float sw = msw[t];
      const float* xrow = x + (size_t)(t0 + t) * H + c;
      float4 xa = *(const float4*)xrow;
      float4 xb = *(const float4*)(xrow + 4);
      float o[8] = {xa.x * sw, xa.y * sw, xa.z * sw, xa.w * sw,
                    xb.x * sw, xb.y * sw, xb.z * sw, xb.w * sw};
#pragma unroll
      for (int k = 0; k < TOPK; ++k) {
        const int e = mi[t][k];
        const float wk = mw[t][k];
        if (USE_WS) {
          bf16x8 bv = *(const bf16x8*)(Bb + (size_t)e * H + c);
#pragma unroll
          for (int i = 0; i < 8; ++i) o[i] += wk * bf2f((unsigned short)bv[i]);
        } else {
          float4 p = *(const float4*)(eb + (size_t)e * H + c);
          float4 q = *(const float4*)(eb + (size_t)e * H + c + 4);
          o[0] += wk * p.x; o[1] += wk * p.y; o[2] += wk * p.z; o[3] += wk * p.w;
          o[4] += wk * q.x; o[5] += wk * q.y; o[6] += wk * q.z; o[7] += wk * q.w;
        }
      }
      float* orow = out + (size_t)(t0 + t) * H + c;
      *(float4*)orow       = make_float4(o[0], o[1], o[2], o[3]);
      *(float4*)(orow + 4) = make_float4(o[4], o[5], o[6], o[7]);
    }
  }
}

extern "C" void kernel_launch(void* const* d_in, const int* in_sizes, int n_in,
                              void* d_out, int out_size, void* d_ws, size_t ws_size,
                              hipStream_t stream) {
  const float* x  = (const float*)d_in[0];
  const float* W  = (const float*)d_in[1];
  const float* rb = (const float*)d_in[2];
  const float* eb = (const float*)d_in[3];
  float* out = (float*)d_out;

  const int T = in_sizes[0] / H;     // 16384
  const int grid = T / TT;           // 1024

  const size_t need = (size_t)2 * E * H * sizeof(unsigned short);  // 512 KB
  if (ws_size >= need) {
    unsigned short* Wb = (unsigned short*)d_ws;
    unsigned short* Bb = Wb + E * H;
    cvt_kernel<<<(2 * E * H) / (256 * 4), 256, 0, stream>>>(W, eb, Wb, Bb);
    moe_kernel<true><<<grid, NT, 0, stream>>>(x, W, rb, eb, Wb, Bb, out);
  } else {
    moe_kernel<false><<<grid, NT, 0, stream>>>(x, W, rb, eb, nullptr, nullptr, out);
  }
}

// Round 4
// 302.902 us; speedup vs baseline: 1.0372x; 1.0372x over previous
//
#include <hip/hip_runtime.h>
#include <hip/hip_bf16.h>
#include <float.h>

#define H 2048
#define E 64
#define TOPK 8
#define TT 8     // tokens per block
#define NT 256   // threads per block (4 waves)
#define XPAD 16  // pad elements per LDS row: stride 4128 B (16B-aligned, 8-bank shift)

typedef __attribute__((ext_vector_type(8))) short bf16x8;
typedef __attribute__((ext_vector_type(4))) float f32x4;
typedef __attribute__((ext_vector_type(4))) unsigned short us4;

__device__ __forceinline__ unsigned short f2bf(float f) {
  unsigned u = __float_as_uint(f);
  u += 0x7fffu + ((u >> 16) & 1u);   // RNE
  return (unsigned short)(u >> 16);
}
__device__ __forceinline__ float bf2f(unsigned short s) {
  return __uint_as_float(((unsigned)s) << 16);
}
__device__ __forceinline__ float wred_max(float v) {
#pragma unroll
  for (int o = 32; o > 0; o >>= 1) v = fmaxf(v, __shfl_xor(v, o));
  return v;
}
__device__ __forceinline__ float wred_sum(float v) {
#pragma unroll
  for (int o = 32; o > 0; o >>= 1) v += __shfl_xor(v, o);
  return v;
}

// Convert router_weight and expert_bias fp32 -> bf16 into workspace (L2-resident).
__global__ __launch_bounds__(256) void cvt_kernel(const float* __restrict__ W,
                                                  const float* __restrict__ eb,
                                                  unsigned short* __restrict__ Wb,
                                                  unsigned short* __restrict__ Bb) {
  int i = (blockIdx.x * 256 + threadIdx.x) * 4;
  const float* src;
  unsigned short* dst;
  int off;
  if (i < E * H) { src = W; dst = Wb; off = i; }
  else           { src = eb; dst = Bb; off = i - E * H; }
  float4 v = *(const float4*)(src + off);
  us4 r;
  r[0] = f2bf(v.x); r[1] = f2bf(v.y); r[2] = f2bf(v.z); r[3] = f2bf(v.w);
  *(us4*)(dst + off) = r;
}

template <bool USE_WS>
__global__ __launch_bounds__(NT, 4) void moe_kernel(
    const float* __restrict__ x, const float* __restrict__ W,
    const float* __restrict__ rb, const float* __restrict__ eb,
    const unsigned short* __restrict__ Wb, const unsigned short* __restrict__ Bb,
    float* __restrict__ out) {
  // ~33 KB LDS total -> 4 blocks/CU co-resident (16 waves/CU), deep cross-block
  // phase pipelining. x read from HBM exactly once (staged here as bf16).
  __shared__ unsigned short xl[TT][H + XPAD];  // 33024 B
  __shared__ float lg[TT][E + 1];              // 2080 B
  __shared__ float msw[TT];
  __shared__ float mw[TT][TOPK];
  __shared__ int   mi[TT][TOPK];

  const int tid = threadIdx.x;
  const int t0  = blockIdx.x * TT;
  const int wv = tid >> 6, lane = tid & 63, quad = lane >> 4, m = lane & 15;

  // ---- Phase A: stage 8 rows of x (contiguous 16K floats) into LDS as bf16 ----
  {
    const float* base = x + (size_t)t0 * H;
#pragma unroll 8
    for (int j = 0; j < 16; ++j) {
      const int p = (tid + j * NT) * 4;        // flat float index in tile
      float4 a = *(const float4*)(base + p);
      us4 r;
      r[0] = f2bf(a.x); r[1] = f2bf(a.y); r[2] = f2bf(a.z); r[3] = f2bf(a.w);
      *(us4*)&xl[p >> 11][p & (H - 1)] = r;
    }
  }
  __syncthreads();

  // ---- Phase B: logits[8 tok x 64 exp] via MFMA; each wave owns 16 experts.
  // A rows 8..15 duplicate rows 0..7 (M-dim half-wasted; MFMA is ~1% utilized).
  {
    const int e = wv * 16 + m;
    f32x4 acc = {0.f, 0.f, 0.f, 0.f};
    const unsigned short* xp = &xl[m & 7][quad * 8];
    if (USE_WS) {
      const unsigned short* wp = Wb + (size_t)e * H + quad * 8;
#pragma unroll 8
      for (int it = 0; it < H / 32; ++it) {
        bf16x8 av = *(const bf16x8*)(xp + it * 32);
        bf16x8 bv = *(const bf16x8*)(wp + it * 32);
        acc = __builtin_amdgcn_mfma_f32_16x16x32_bf16(av, bv, acc, 0, 0, 0);
      }
    } else {
      const float* wp = W + (size_t)e * H + quad * 8;
#pragma unroll 4
      for (int it = 0; it < H / 32; ++it) {
        bf16x8 av = *(const bf16x8*)(xp + it * 32);
        float4 p = *(const float4*)(wp + it * 32);
        float4 q = *(const float4*)(wp + it * 32 + 4);
        bf16x8 bv;
        bv[0] = (short)f2bf(p.x); bv[1] = (short)f2bf(p.y);
        bv[2] = (short)f2bf(p.z); bv[3] = (short)f2bf(p.w);
        bv[4] = (short)f2bf(q.x); bv[5] = (short)f2bf(q.y);
        bv[6] = (short)f2bf(q.z); bv[7] = (short)f2bf(q.w);
        acc = __builtin_amdgcn_mfma_f32_16x16x32_bf16(av, bv, acc, 0, 0, 0);
      }
    }
    // C/D layout: col = lane&15 (expert-in-tile), row = quad*4+reg (token).
    // Rows 8..15 are duplicates -> only quads 0,1 write.
    if (quad < 2) {
#pragma unroll
      for (int r = 0; r < 4; ++r) lg[quad * 4 + r][wv * 16 + m] = acc[r];
    }
  }
  __syncthreads();

  // ---- Phase B': softmax + top-8. Wave wv handles tokens 2wv, 2wv+1; lane = expert.
  {
#pragma unroll
    for (int tt = 0; tt < 2; ++tt) {
      const int t = wv * 2 + tt;
      float l = lg[t][lane] + rb[lane];
      const float mx = wred_max(l);
      const float p = expf(l - mx);
      const float inv = 1.f / wred_sum(p);
      float sumw = 0.f;
      float lsel = l;
#pragma unroll
      for (int k = 0; k < TOPK; ++k) {
        const float mk = wred_max(lsel);
        const unsigned long long b = __ballot(lsel == mk);
        const int idx = __ffsll(b) - 1;          // tie -> lowest index (matches top_k)
        const float wk = expf(mk - mx) * inv;
        sumw += wk;
        if (lane == 0) { mw[t][k] = wk; mi[t][k] = idx; }
        if (lane == idx) lsel = -FLT_MAX;
      }
      if (lane == 0) msw[t] = sumw;
    }
  }
  __syncthreads();

  // ---- Phase C: out[t][h] = x[t][h]*sum_w + sum_k w_k * bias[idx_k][h] ----
  {
    const int c = tid * 8;  // 0..2040, 256 threads cover a full row
#pragma unroll 2
    for (int t = 0; t < TT; ++t) {
      const float sw = msw[t];
      bf16x8 xv = *(const bf16x8*)&xl[t][c];
      float o[8];
#pragma unroll
      for (int i = 0; i < 8; ++i) o[i] = bf2f((unsigned short)xv[i]) * sw;
#pragma unroll
      for (int k = 0; k < TOPK; ++k) {
        const int e = mi[t][k];
        const float wk = mw[t][k];
        if (USE_WS) {
          bf16x8 bv = *(const bf16x8*)(Bb + (size_t)e * H + c);
#pragma unroll
          for (int i = 0; i < 8; ++i) o[i] += wk * bf2f((unsigned short)bv[i]);
        } else {
          float4 p = *(const float4*)(eb + (size_t)e * H + c);
          float4 q = *(const float4*)(eb + (size_t)e * H + c + 4);
          o[0] += wk * p.x; o[1] += wk * p.y; o[2] += wk * p.z; o[3] += wk * p.w;
          o[4] += wk * q.x; o[5] += wk * q.y; o[6] += wk * q.z; o[7] += wk * q.w;
        }
      }
      float* orow = out + (size_t)(t0 + t) * H + c;
      *(float4*)orow       = make_float4(o[0], o[1], o[2], o[3]);
      *(float4*)(orow + 4) = make_float4(o[4], o[5], o[6], o[7]);
    }
  }
}

extern "C" void kernel_launch(void* const* d_in, const int* in_sizes, int n_in,
                              void* d_out, int out_size, void* d_ws, size_t ws_size,
                              hipStream_t stream) {
  const float* x  = (const float*)d_in[0];
  const float* W  = (const float*)d_in[1];
  const float* rb = (const float*)d_in[2];
  const float* eb = (const float*)d_in[3];
  float* out = (float*)d_out;

  const int T = in_sizes[0] / H;     // 16384
  const int grid = T / TT;           // 2048

  const size_t need = (size_t)2 * E * H * sizeof(unsigned short);  // 512 KB
  if (ws_size >= need) {
    unsigned short* Wb = (unsigned short*)d_ws;
    unsigned short* Bb = Wb + E * H;
    cvt_kernel<<<(2 * E * H) / (256 * 4), 256, 0, stream>>>(W, eb, Wb, Bb);
    moe_kernel<true><<<grid, NT, 0, stream>>>(x, W, rb, eb, Wb, Bb, out);
  } else {
    moe_kernel<false><<<grid, NT, 0, stream>>>(x, W, rb, eb, nullptr, nullptr, out);
  }
}